// Round 1
// baseline (638.229 us; speedup 1.0000x reference)
//
#include <hip/hip_runtime.h>

// Problem constants (from reference)
#define NB 32     // batch
#define NT 2000   // time steps
#define NH 256    // hidden
#define NS 63     // states
#define TM 16     // t-rows per block in trans kernel
#define TP 64     // padded row stride for trans in workspace

// Kernel 1: trans[b,t,:] = relu([e[t+1], e[t]] @ W1 + b1) @ W2 + b2 for t in [0, NT-2]
// Decompose: h = relu(e[t+1] @ W1_top + e[t] @ W1_bot + b1).
// Block handles TM consecutive t-rows for one batch b. 256 threads; thread j owns
// hidden column j. e-row values are wave-uniform -> scalar loads (SGPR broadcast);
// W1[k*NH + j] is coalesced across threads.
__global__ __launch_bounds__(256) void trans_kernel(
    const float* __restrict__ E, const float* __restrict__ W1,
    const float* __restrict__ b1, const float* __restrict__ W2,
    const float* __restrict__ b2, float* __restrict__ trans) {
  const int b = blockIdx.y;
  const int t0 = blockIdx.x * TM;
  const int nrows = min(TM, (NT - 1) - t0);
  const int tid = threadIdx.x;

  __shared__ float sh[TM][NH];

  float acc[TM];
  #pragma unroll
  for (int r = 0; r < TM; ++r) acc[r] = b1[tid];

  const float* Eb = E + (size_t)b * NT * NH;

  #pragma unroll 1
  for (int k = 0; k < NH; k += 4) {
    // e values for rows t0..t0+TM (uniform across the wave -> s_load)
    float ev[TM + 1][4];
    #pragma unroll
    for (int i = 0; i <= TM; ++i) {
      const int tr = min(t0 + i, NT - 1);  // clamp: rows beyond nrows unused
      const float4 v = *(const float4*)&Eb[(size_t)tr * NH + k];
      ev[i][0] = v.x; ev[i][1] = v.y; ev[i][2] = v.z; ev[i][3] = v.w;
    }
    #pragma unroll
    for (int kk = 0; kk < 4; ++kk) {
      const float w1t = W1[(k + kk) * NH + tid];        // rows 0..255  (e[t+1] part)
      const float w1b = W1[(k + kk + NH) * NH + tid];   // rows 256..511 (e[t] part)
      #pragma unroll
      for (int r = 0; r < TM; ++r) {
        acc[r] = fmaf(ev[r + 1][kk], w1t, acc[r]);
        acc[r] = fmaf(ev[r][kk], w1b, acc[r]);
      }
    }
  }

  #pragma unroll
  for (int r = 0; r < TM; ++r) sh[r][tid] = fmaxf(acc[r], 0.f);
  __syncthreads();

  // Stage 2: trans_row = h @ W2 + b2. Wave w handles rows w, w+4, ...
  const int w = tid >> 6, lane = tid & 63;
  for (int r = w; r < nrows; r += 4) {
    if (lane < NS) {
      float a2 = b2[lane];
      #pragma unroll 4
      for (int k = 0; k < NH; k += 4) {
        const float4 hv = *(const float4*)&sh[r][k];
        a2 = fmaf(hv.x, W2[(k + 0) * NS + lane], a2);
        a2 = fmaf(hv.y, W2[(k + 1) * NS + lane], a2);
        a2 = fmaf(hv.z, W2[(k + 2) * NS + lane], a2);
        a2 = fmaf(hv.w, W2[(k + 3) * NS + lane], a2);
      }
      trans[((size_t)b * (NT - 1) + t0 + r) * TP + lane] = a2;
    }
  }
}

// Kernel 2: one wave per (b,t): scores -> softmax over 63 states.
__global__ __launch_bounds__(256) void align_kernel(
    const float* __restrict__ logits, const int* __restrict__ kw,
    const float* __restrict__ trans, float* __restrict__ out) {
  const int gw = blockIdx.x * 4 + (threadIdx.x >> 6);  // global wave = b*NT + t
  const int lane = threadIdx.x & 63;
  const int b = gw / NT;
  const int t = gw - b * NT;
  const float* lb = logits + (size_t)b * NT * NS;
  const float* trb = trans + (size_t)b * (NT - 1) * TP;

  float score;
  if (t == 0) {
    // need actual logp[b,0,kw] = logits[b,0,kw] - LSE(logits[b,0,:])
    float v = (lane < NS) ? lb[lane] : -1e30f;
    float m = v;
    #pragma unroll
    for (int o = 32; o > 0; o >>= 1) m = fmaxf(m, __shfl_xor(m, o));
    float e = (lane < NS) ? __expf(v - m) : 0.f;
    float s = e;
    #pragma unroll
    for (int o = 32; o > 0; o >>= 1) s += __shfl_xor(s, o);
    const float lse = m + __logf(s);
    const int k0 = kw[b * 32];
    const float f00 = lb[k0] - lse;  // f0[b,0]
    score = (lane < NS) ? ((lane == 0) ? f00 : 0.f) + lb[NS + lane] + trb[lane]
                        : -1e30f;
  } else if (t == NT - 1) {
    score = (lane < NS)
        ? lb[(size_t)(NT - 1) * NS + lane] + trb[(size_t)(NT - 2) * TP + lane]
        : -1e30f;
  } else {
    score = (lane < NS)
        ? lb[(size_t)t * NS + lane] + lb[(size_t)(t + 1) * NS + lane] +
          trb[(size_t)(t - 1) * TP + lane] + trb[(size_t)t * TP + lane]
        : -1e30f;
  }

  float m = score;
  #pragma unroll
  for (int o = 32; o > 0; o >>= 1) m = fmaxf(m, __shfl_xor(m, o));
  float e = (lane < NS) ? __expf(score - m) : 0.f;
  float s = e;
  #pragma unroll
  for (int o = 32; o > 0; o >>= 1) s += __shfl_xor(s, o);
  if (lane < NS) out[(size_t)gw * NS + lane] = e / s;
}

extern "C" void kernel_launch(void* const* d_in, const int* in_sizes, int n_in,
                              void* d_out, int out_size, void* d_ws, size_t ws_size,
                              hipStream_t stream) {
  const float* logits = (const float*)d_in[0];  // (B,T,S)
  const float* E      = (const float*)d_in[1];  // (B,T,H)
  const int*   kw     = (const int*)d_in[2];    // (B,32)
  const float* W1     = (const float*)d_in[3];  // (2H,H)
  const float* b1     = (const float*)d_in[4];  // (H,)
  const float* W2     = (const float*)d_in[5];  // (H,S)
  const float* b2     = (const float*)d_in[6];  // (S,)
  float* out   = (float*)d_out;
  float* trans = (float*)d_ws;  // (B, NT-1, TP) floats = 16.4 MB

  dim3 g1((NT - 1 + TM - 1) / TM, NB);  // 125 x 32 blocks
  trans_kernel<<<g1, 256, 0, stream>>>(E, W1, b1, W2, b2, trans);
  align_kernel<<<NB * NT / 4, 256, 0, stream>>>(logits, kw, trans, out);
}

// Round 2
// 183.501 us; speedup vs baseline: 3.4781x; 3.4781x over previous
//
#include <hip/hip_runtime.h>
#include <stdint.h>

#define NB 32
#define NT 2000
#define NH 256
#define NS 63
#define NTM1 1999    // NT-1
#define LDSROW 264   // padded bf16 row stride (+8 breaks bank alignment)

typedef __attribute__((ext_vector_type(8))) short bf16x8;
typedef __attribute__((ext_vector_type(4))) float f32x4;

__device__ inline unsigned short f2bf(float f) {
  union { float f; uint32_t u; } v; v.f = f;
  return (unsigned short)((v.u + 0x7fffu + ((v.u >> 16) & 1u)) >> 16);  // RNE
}
__device__ inline float bf2f(unsigned short b) {
  union { uint32_t u; float f; } v; v.u = ((uint32_t)b) << 16;
  return v.f;
}

// W1 (512x256 f32) -> W1T bf16 [n=0..255][k=0..511]  (W1T[n][k] = W1[k][n])
// W2 (256x63 f32)  -> W2T bf16 [n=0..63][k=0..255]   (col 63 zero-padded)
__global__ __launch_bounds__(256) void convert_kernel(
    const float* __restrict__ W1, const float* __restrict__ W2,
    unsigned short* __restrict__ W1T, unsigned short* __restrict__ W2T) {
  int idx = blockIdx.x * 256 + threadIdx.x;
  if (idx < 512 * 256) {
    int n = idx >> 9, k = idx & 511;
    W1T[idx] = f2bf(W1[k * NH + n]);
  } else {
    int j = idx - 512 * 256;
    int n = j >> 8, k = j & 255;
    W2T[j] = f2bf(n < NS ? W2[k * NS + n] : 0.f);
  }
}

// Block: one batch b, 64 t-rows. Wave w owns hidden cols n0=w*64.
// GEMM1: h[r][j] = sum_k e[r+1][k] W1T[j][k] + e[r][k] W1T[j][256+k]
// GEMM2: trans[r][s] = relu(h)[r][:] @ W2 + b2  (MFMA, N padded to 64)
__global__ __launch_bounds__(256) void trans_mfma_kernel(
    const float* __restrict__ E, const unsigned short* __restrict__ W1T,
    const float* __restrict__ b1, const unsigned short* __restrict__ W2T,
    const float* __restrict__ b2, unsigned short* __restrict__ trans) {
  const int b = blockIdx.y;
  const int t0 = blockIdx.x * 64;
  const int tid = threadIdx.x;
  const int w = tid >> 6;
  const int lane = tid & 63;
  const int quad = lane >> 4;
  const int l16 = lane & 15;

  __shared__ unsigned short lds[65 * LDSROW];  // 34.3 KB; E-tile then reused for h

  // Stage E rows t0..t0+64 (clamped at NT-1), f32 -> bf16, padded stride
  const float* Eb = E + (size_t)b * NT * NH;
  for (int i = tid; i < 65 * 64; i += 256) {
    int row = i >> 6, c4 = (i & 63) << 2;
    int tr = t0 + row; if (tr > NT - 1) tr = NT - 1;
    float4 v = *(const float4*)&Eb[(size_t)tr * NH + c4];
    ushort4 o;
    o.x = f2bf(v.x); o.y = f2bf(v.y); o.z = f2bf(v.z); o.w = f2bf(v.w);
    *(ushort4*)&lds[row * LDSROW + c4] = o;
  }
  __syncthreads();

  const int n0 = w * 64;
  f32x4 acc[4][4];
  #pragma unroll
  for (int tm = 0; tm < 4; ++tm)
    #pragma unroll
    for (int tn = 0; tn < 4; ++tn) acc[tm][tn] = (f32x4){0.f, 0.f, 0.f, 0.f};

  #pragma unroll
  for (int half = 0; half < 2; ++half) {
    const int aoff = (half == 0) ? 1 : 0;  // top half of W1 pairs with e[t+1]
    #pragma unroll 2
    for (int k0 = 0; k0 < 256; k0 += 32) {
      bf16x8 af[4], bfr[4];
      #pragma unroll
      for (int tm = 0; tm < 4; ++tm)
        af[tm] = *(const bf16x8*)&lds[(tm * 16 + l16 + aoff) * LDSROW + k0 + quad * 8];
      #pragma unroll
      for (int tn = 0; tn < 4; ++tn)
        bfr[tn] = *(const bf16x8*)&W1T[(size_t)(n0 + tn * 16 + l16) * 512 +
                                       half * 256 + k0 + quad * 8];
      #pragma unroll
      for (int tm = 0; tm < 4; ++tm)
        #pragma unroll
        for (int tn = 0; tn < 4; ++tn)
          acc[tm][tn] = __builtin_amdgcn_mfma_f32_16x16x32_bf16(
              af[tm], bfr[tn], acc[tm][tn], 0, 0, 0);
    }
  }
  __syncthreads();  // all A-reads done before overwriting lds with h

  // h = relu(acc + b1) -> bf16 LDS (C layout: row=quad*4+r, col=l16 per 16x16 tile)
  #pragma unroll
  for (int tn = 0; tn < 4; ++tn) {
    float b1v = b1[n0 + tn * 16 + l16];
    #pragma unroll
    for (int tm = 0; tm < 4; ++tm)
      #pragma unroll
      for (int r = 0; r < 4; ++r) {
        float hv = fmaxf(acc[tm][tn][r] + b1v, 0.f);
        lds[(tm * 16 + quad * 4 + r) * LDSROW + n0 + tn * 16 + l16] = f2bf(hv);
      }
  }
  __syncthreads();

  // GEMM2: wave w takes rows m0..m0+15, all 64 (padded) s-cols
  const int m0 = w * 16;
  f32x4 acc2[4];
  #pragma unroll
  for (int tn = 0; tn < 4; ++tn) acc2[tn] = (f32x4){0.f, 0.f, 0.f, 0.f};

  #pragma unroll 2
  for (int k0 = 0; k0 < 256; k0 += 32) {
    bf16x8 af = *(const bf16x8*)&lds[(m0 + l16) * LDSROW + k0 + quad * 8];
    #pragma unroll
    for (int tn = 0; tn < 4; ++tn) {
      bf16x8 bfv = *(const bf16x8*)&W2T[(size_t)(tn * 16 + l16) * 256 + k0 + quad * 8];
      acc2[tn] = __builtin_amdgcn_mfma_f32_16x16x32_bf16(af, bfv, acc2[tn], 0, 0, 0);
    }
  }

  unsigned short* trb = trans + (size_t)b * NTM1 * 64;
  #pragma unroll
  for (int tn = 0; tn < 4; ++tn) {
    int s = tn * 16 + l16;
    float b2v = (s < NS) ? b2[s] : 0.f;
    #pragma unroll
    for (int r = 0; r < 4; ++r) {
      int trow = t0 + m0 + quad * 4 + r;
      if (s < NS && trow < NTM1)
        trb[(size_t)trow * 64 + s] = f2bf(acc2[tn][r] + b2v);
    }
  }
}

// One wave per (b,t): build scores, softmax over 63 states.
__global__ __launch_bounds__(256) void align_kernel(
    const float* __restrict__ logits, const int* __restrict__ kw,
    const unsigned short* __restrict__ trans, float* __restrict__ out) {
  const int gw = blockIdx.x * 4 + (threadIdx.x >> 6);
  const int lane = threadIdx.x & 63;
  const int b = gw / NT;
  const int t = gw - b * NT;
  const float* lb = logits + (size_t)b * NT * NS;
  const unsigned short* trb = trans + (size_t)b * NTM1 * 64;

  float score;
  if (t == 0) {
    float v = (lane < NS) ? lb[lane] : -1e30f;
    float m = v;
    #pragma unroll
    for (int o = 32; o > 0; o >>= 1) m = fmaxf(m, __shfl_xor(m, o));
    float e = (lane < NS) ? __expf(v - m) : 0.f;
    float s = e;
    #pragma unroll
    for (int o = 32; o > 0; o >>= 1) s += __shfl_xor(s, o);
    const float lse = m + __logf(s);
    const int k0 = kw[b * 32];
    const float f00 = lb[k0] - lse;
    score = (lane < NS) ? ((lane == 0) ? f00 : 0.f) + lb[NS + lane] + bf2f(trb[lane])
                        : -1e30f;
  } else if (t == NT - 1) {
    score = (lane < NS)
        ? lb[(size_t)(NT - 1) * NS + lane] + bf2f(trb[(size_t)(NT - 2) * 64 + lane])
        : -1e30f;
  } else {
    score = (lane < NS)
        ? lb[(size_t)t * NS + lane] + lb[(size_t)(t + 1) * NS + lane] +
          bf2f(trb[(size_t)(t - 1) * 64 + lane]) + bf2f(trb[(size_t)t * 64 + lane])
        : -1e30f;
  }

  float m = score;
  #pragma unroll
  for (int o = 32; o > 0; o >>= 1) m = fmaxf(m, __shfl_xor(m, o));
  float e = (lane < NS) ? __expf(score - m) : 0.f;
  float s = e;
  #pragma unroll
  for (int o = 32; o > 0; o >>= 1) s += __shfl_xor(s, o);
  if (lane < NS) out[(size_t)gw * NS + lane] = e / s;
}

extern "C" void kernel_launch(void* const* d_in, const int* in_sizes, int n_in,
                              void* d_out, int out_size, void* d_ws, size_t ws_size,
                              hipStream_t stream) {
  const float* logits = (const float*)d_in[0];
  const float* E      = (const float*)d_in[1];
  const int*   kw     = (const int*)d_in[2];
  const float* W1     = (const float*)d_in[3];
  const float* b1     = (const float*)d_in[4];
  const float* W2     = (const float*)d_in[5];
  const float* b2     = (const float*)d_in[6];
  float* out = (float*)d_out;

  // ws layout: trans bf16 (32*1999*64*2 = 8,187,904 B), W1T (262,144 B), W2T (32,768 B)
  unsigned short* trans = (unsigned short*)d_ws;
  unsigned short* W1T = (unsigned short*)((char*)d_ws + (size_t)NB * NTM1 * 64 * 2);
  unsigned short* W2T = W1T + 512 * 256;

  convert_kernel<<<576, 256, 0, stream>>>(W1, W2, W1T, W2T);
  dim3 g1((NTM1 + 63) / 64, NB);  // 32 x 32
  trans_mfma_kernel<<<g1, 256, 0, stream>>>(E, W1T, b1, W2T, b2, trans);
  align_kernel<<<NB * NT / 4, 256, 0, stream>>>(logits, kw, trans, out);
}